// Round 9
// baseline (149.644 us; speedup 1.0000x reference)
//
#include <hip/hip_runtime.h>

// AlignOnlySubLayer: out[b,m,d] = main[b,m,d] - sum_c softmax_m(C·M^T)[c,m] * C[c,d]
// B=8, Lc=Lm=2048, D=128, fp32 in/out.
// Round-18: attend m-tile 64. R17 landed as predicted (stats tile-64: -8us).
// attend was left with ~512 MB of c-side L2 reads (m-tile 32: 512 blocks x
// ~1 MB Cf+Ctf) at only 2 waves/SIMD. v3: 256 blocks x 512 thr (8 waves =
// 2 mg x 4 ch), same 64 KB LDS -> 2 blocks/CU = 4 waves/SIMD (2x latency
// hiding) and the two mg-waves sharing a ch hit the SAME Cf/Ctf records
// (L1 broadcast) -> c-side traffic per output halves. Per-wave body is the
// R16-proven code verbatim (only mw = mtile*2+mg changes). Epilogue reuses
// the 64 KB red[] in two mg-phases.
// convert/stats: R17 bodies verbatim.
// Record layouts (la=l&31, hi=l>>5, e=0..7):
//   Cf [((b*16+cs)*4+ch)*8+ks]          lane l = C[cs*128+ch*32+la][(ks*2+hi)*8+e]
//   Mf [(b*64+mw)*8+ks]                 lane l = M[mw*32+la][(ks*2+hi)*8+e]
//   Ctf[(((b*16+cs)*4+ch)*4+dg)*2+ks2]  lane l = C[cs*128+(ch*4+ks2*2+hi)*8+e][dg*32+la]
// MFMA frag layout (32x32x16, verified R9-R17): A/B lane (la,hi) holds
// row/col la, k = hi*8+e; D: col=la, row=(r&3)+8*(r>>2)+4*hi.

#define BATCH 8
#define L_SEQ 2048
#define DD 128
#define SHIFT 40.0f
#define LDA 136   // fallback padded stride
#define TLD 136   // convert LDS tile stride (shorts)

typedef __attribute__((ext_vector_type(8))) short bf16x8;
typedef __attribute__((ext_vector_type(4))) float f32x4;
typedef __attribute__((ext_vector_type(16))) float f32x16;
typedef __attribute__((ext_vector_type(4))) unsigned int uint4v;

__device__ __forceinline__ short f2bf(float f) {
    unsigned u = __builtin_bit_cast(unsigned, f);
    return (short)((u + 0x8000u) >> 16);
}

// fp32 global (rows of 128) -> bf16 LDS tile, stride LDA (fallback path only).
template <int NT>
__device__ __forceinline__ void stage_tile(short* __restrict__ dst,
                                           const float* __restrict__ src,
                                           int nelts, int t) {
    for (int base = 0; base < nelts; base += NT * 8) {
        int flat = base + t * 8;
        const float4* p = (const float4*)(src + flat);
        float4 v0 = p[0];
        float4 v1 = p[1];
        bf16x8 s;
        s[0] = f2bf(v0.x); s[1] = f2bf(v0.y); s[2] = f2bf(v0.z); s[3] = f2bf(v0.w);
        s[4] = f2bf(v1.x); s[5] = f2bf(v1.y); s[6] = f2bf(v1.z); s[7] = f2bf(v1.w);
        int row = flat >> 7;
        int col = flat & 127;
        *(bf16x8*)&dst[row * LDA + col] = s;
    }
}

__global__ __launch_bounds__(256) void zero_kernel(float* __restrict__ p, int n) {
    int i = blockIdx.x * 256 + threadIdx.x;
    if (i < n) p[i] = 0.0f;
}

// ---------------------------------------------------------------------------
// Fast path
// ---------------------------------------------------------------------------

// grid = 2 tensors x 8 b x 64 rowgroups = 1024 blocks, 256 thr.
// Stages a 32-row fp32 tile -> bf16 LDS, then emits fragment records.
__global__ __launch_bounds__(256) void convert_kernel(const float* __restrict__ ctx,
                                                      const float* __restrict__ mn,
                                                      short* __restrict__ Cf,
                                                      short* __restrict__ Mf,
                                                      short* __restrict__ Ctf) {
    __shared__ short Ts[32 * TLD];

    int bid = blockIdx.x;
    int tsel = bid & 1;
    int b = (bid >> 1) & 7;
    int rg = bid >> 4;          // 0..63 : 32-row group
    int t = threadIdx.x;

    const float* src = (tsel ? mn : ctx) + ((size_t)(b * L_SEQ + rg * 32)) * DD;

    #pragma unroll
    for (int i = 0; i < 2; ++i) {
        int flat = i * 2048 + t * 8;
        int r = flat >> 7;
        int d = flat & 127;
        const float4* p = (const float4*)(src + flat);
        float4 v0 = p[0];
        float4 v1 = p[1];
        bf16x8 s;
        s[0] = f2bf(v0.x); s[1] = f2bf(v0.y); s[2] = f2bf(v0.z); s[3] = f2bf(v0.w);
        s[4] = f2bf(v1.x); s[5] = f2bf(v1.y); s[6] = f2bf(v1.z); s[7] = f2bf(v1.w);
        *(bf16x8*)&Ts[r * TLD + d] = s;
    }
    __syncthreads();

    if (tsel == 0) {
        int cs = rg >> 2;
        int ch = rg & 3;
        // Cf: 8 records (ks), 64 lane-slots each; 2 slots/thread.
        size_t cfb = (size_t)(((b * 16 + cs) * 4 + ch) * 8) * 512;
        #pragma unroll
        for (int i = 0; i < 2; ++i) {
            int slot = i * 256 + t;
            int ks = slot >> 6;
            int l2 = slot & 63;
            int la = l2 & 31;
            int hi = l2 >> 5;
            bf16x8 v = *(const bf16x8*)&Ts[la * TLD + (ks * 2 + hi) * 8];
            *(bf16x8*)&Cf[cfb + (size_t)ks * 512 + l2 * 8] = v;
        }
        // Ctf: 8 records (dg,ks2); transpose gather from LDS.
        size_t ctb = (size_t)((((b * 16 + cs) * 4 + ch) * 4) * 2) * 512;
        #pragma unroll
        for (int i = 0; i < 2; ++i) {
            int slot = i * 256 + t;
            int recl = slot >> 6;       // dg*2 + ks2
            int l2 = slot & 63;
            int dg = recl >> 1;
            int ks2 = recl & 1;
            int la = l2 & 31;
            int hi = l2 >> 5;
            int d = dg * 32 + la;
            int c0 = (ks2 * 2 + hi) * 8;     // local c row base
            bf16x8 v;
            #pragma unroll
            for (int j = 0; j < 8; ++j) v[j] = Ts[(c0 + j) * TLD + d];
            *(bf16x8*)&Ctf[ctb + (size_t)recl * 512 + l2 * 8] = v;
        }
    } else {
        // Mf: 8 records (ks); rowgroup rg = mw.
        size_t mfb = (size_t)((b * 64 + rg) * 8) * 512;
        #pragma unroll
        for (int i = 0; i < 2; ++i) {
            int slot = i * 256 + t;
            int ks = slot >> 6;
            int l2 = slot & 63;
            int la = l2 & 31;
            int hi = l2 >> 5;
            bf16x8 v = *(const bf16x8*)&Ts[la * TLD + (ks * 2 + hi) * 8];
            *(bf16x8*)&Mf[mfb + (size_t)ks * 512 + l2 * 8] = v;
        }
    }
}

// grid = 8 b x 32 ct2(64 c) = 256 blocks (b = bid&7), 512 thr (8 waves).
// Swapped S: D[i=m][j=c=la] = mfma(Mf, Cf). c-tile 64: cf[2][8] hoisted,
// TWO independent accumulator chains per Mf load. Writes invL directly.
__global__ __launch_bounds__(512) void stats_kernel(const short* __restrict__ Cf,
                                                    const short* __restrict__ Mf,
                                                    float* __restrict__ invLg) {
    __shared__ float red[8][2][32];

    int bid = blockIdx.x;
    int b = bid & 7;
    int ct2 = bid >> 3;         // 0..31 : 64-c tile
    int t = threadIdx.x;
    int w = t >> 6;             // 0..7
    int l = t & 63;
    int la = l & 31;

    // Hoist C B-frags for the two 32-c subtiles (ct = ct2*2 + j).
    bf16x8 cf[2][8];
    #pragma unroll
    for (int j = 0; j < 2; ++j) {
        int ct = ct2 * 2 + j;
        const short* cfp = Cf + (size_t)(((b * 16 + (ct >> 2)) * 4 + (ct & 3)) * 8) * 512 + l * 8;
        #pragma unroll
        for (int ks = 0; ks < 8; ++ks)
            cf[j][ks] = *(const bf16x8*)&cfp[(size_t)ks * 512];
    }

    float lacc0 = 0.0f, lacc1 = 0.0f;
    for (int i = 0; i < 8; ++i) {
        int mw = w * 8 + i;
        const short* mfp = Mf + (size_t)((b * 64 + mw) * 8) * 512 + l * 8;
        f32x16 s0, s1;
        #pragma unroll
        for (int r = 0; r < 16; ++r) { s0[r] = 0.0f; s1[r] = 0.0f; }
        #pragma unroll
        for (int ks = 0; ks < 8; ++ks) {
            bf16x8 av = *(const bf16x8*)&mfp[(size_t)ks * 512];
            s0 = __builtin_amdgcn_mfma_f32_32x32x16_bf16(av, cf[0][ks], s0, 0, 0, 0);
            s1 = __builtin_amdgcn_mfma_f32_32x32x16_bf16(av, cf[1][ks], s1, 0, 0, 0);
        }
        #pragma unroll
        for (int r = 0; r < 16; ++r) {
            lacc0 += __expf(s0[r] - SHIFT);
            lacc1 += __expf(s1[r] - SHIFT);
        }
    }

    // lanes l and l+32 hold the same c (col=la), disjoint m rows: combine,
    // then reduce the 8 waves through 2 KB LDS.
    lacc0 += __shfl_xor(lacc0, 32);
    lacc1 += __shfl_xor(lacc1, 32);
    if (l < 32) { red[w][0][la] = lacc0; red[w][1][la] = lacc1; }
    __syncthreads();
    if (t < 64) {
        int j = t >> 5;
        int c = t & 31;
        float L = 0.0f;
        #pragma unroll
        for (int ww = 0; ww < 8; ++ww) L += red[ww][j][c];
        invLg[(size_t)b * L_SEQ + ct2 * 64 + j * 32 + c] = 1.0f / L;
    }
}

// grid = 8 b x 32 mtiles(64 m) = 256 blocks (b = bid&7), 512 thr = 8 waves
// (2 mg x 4 ch). All operands coalesced records; NO main-loop barriers.
// LDS 64 KB epilogue-only, reused across the two mg phases -> 2 blocks/CU =
// 4 waves/SIMD. mg-waves sharing a ch read identical Cf/Ctf records (L1 hit).
__global__ __launch_bounds__(512, 2) void attend_fused(const short* __restrict__ Cf,
                                                       const short* __restrict__ Mf,
                                                       const short* __restrict__ Ctf,
                                                       const float* __restrict__ invLg,
                                                       const float* __restrict__ mn,
                                                       float* __restrict__ out) {
    __shared__ float red[4][4096];

    int bid = blockIdx.x;
    int b = bid & 7;
    int mtile = bid >> 3;       // 0..31 (64 m each)
    int t = threadIdx.x;
    int w = t >> 6;             // 0..7
    int l = t & 63;
    int la = l & 31;
    int hi = l >> 5;
    int ch = w & 3;
    int mg = w >> 2;            // 0,1

    // Hoist M B-frags: row group mw = mtile*2 + mg.
    bf16x8 mf[8];
    {
        const short* mfp = Mf + (size_t)((b * 64 + mtile * 2 + mg) * 8) * 512 + l * 8;
        #pragma unroll
        for (int ks = 0; ks < 8; ++ks)
            mf[ks] = *(const bf16x8*)&mfp[(size_t)ks * 512];
    }

    f32x16 o[4];
    #pragma unroll
    for (int dg = 0; dg < 4; ++dg)
        #pragma unroll
        for (int r = 0; r < 16; ++r) o[dg][r] = 0.0f;

    const float* ilbase = invLg + (size_t)b * L_SEQ + ch * 32 + hi * 4;

    for (int cs = 0; cs < 16; ++cs) {
        const short* cfp = Cf + (size_t)(((b * 16 + cs) * 4 + ch) * 8) * 512 + l * 8;
        const short* tfp = Ctf + (size_t)((((b * 16 + cs) * 4 + ch) * 4) * 2) * 512 + l * 8;

        // PV A-frags: 8 coalesced record loads (independent of S, fly early).
        bf16x8 tv[4][2];
        #pragma unroll
        for (int dg = 0; dg < 4; ++dg)
            #pragma unroll
            for (int ks2 = 0; ks2 < 2; ++ks2)
                tv[dg][ks2] = *(const bf16x8*)&tfp[(size_t)(dg * 2 + ks2) * 512];

        // invL for this window's 16 c's per lane (broadcast float4 loads).
        f32x4 ilv[4];
        #pragma unroll
        for (int q = 0; q < 4; ++q)
            ilv[q] = *(const f32x4*)&ilbase[cs * 128 + q * 8];

        // S-GEMM (swapped): D[i=c][j=m=la], A = Cf records.
        f32x16 s;
        #pragma unroll
        for (int r = 0; r < 16; ++r) s[r] = 0.0f;
        #pragma unroll
        for (int ks = 0; ks < 8; ++ks) {
            bf16x8 av = *(const bf16x8*)&cfp[(size_t)ks * 512];
            s = __builtin_amdgcn_mfma_f32_32x32x16_bf16(av, mf[ks], s, 0, 0, 0);
        }

        // P = exp(S-40) * invL[c] -> bf16 pairs. reg r=q*4+sub: c_local = sub+8q+4hi.
        unsigned u[4][2];
        #pragma unroll
        for (int q = 0; q < 4; ++q)
            #pragma unroll
            for (int jj = 0; jj < 2; ++jj) {
                float e0 = __expf(s[q * 4 + jj * 2]     - SHIFT) * ilv[q][jj * 2];
                float e1 = __expf(s[q * 4 + jj * 2 + 1] - SHIFT) * ilv[q][jj * 2 + 1];
                u[q][jj] = ((unsigned)(unsigned short)f2bf(e1) << 16)
                         |  (unsigned)(unsigned short)f2bf(e0);
            }

        // Half-wave exchange -> PV B-frags (c_local = ks2*16 + hi*8 + 0..7).
        bf16x8 pa[2];
        #pragma unroll
        for (int ks2 = 0; ks2 < 2; ++ks2) {
            unsigned a0 = u[2 * ks2][0],     a1 = u[2 * ks2][1];
            unsigned b0 = u[2 * ks2 + 1][0], b1 = u[2 * ks2 + 1][1];
            unsigned a0p = (unsigned)__shfl_xor((int)a0, 32);
            unsigned a1p = (unsigned)__shfl_xor((int)a1, 32);
            unsigned b0p = (unsigned)__shfl_xor((int)b0, 32);
            unsigned b1p = (unsigned)__shfl_xor((int)b1, 32);
            uint4v pw;
            pw.x = hi ? b0p : a0;
            pw.y = hi ? b1p : a1;
            pw.z = hi ? b0  : a0p;
            pw.w = hi ? b1  : a1p;
            pa[ks2] = __builtin_bit_cast(bf16x8, pw);
        }

        // PV: D2[i=d][j=m], A = tv (Ctf records), B = pa.
        #pragma unroll
        for (int dg = 0; dg < 4; ++dg)
            #pragma unroll
            for (int ks2 = 0; ks2 < 2; ++ks2)
                o[dg] = __builtin_amdgcn_mfma_f32_32x32x16_bf16(tv[dg][ks2], pa[ks2], o[dg], 0, 0, 0);
    }

    // Epilogue: two mg phases share the 64 KB red[]; out = main - sum(4 ch).
    #pragma unroll
    for (int p = 0; p < 2; ++p) {
        __syncthreads();
        if (mg == p) {
            float* base = red[ch];
            #pragma unroll
            for (int dg = 0; dg < 4; ++dg)
                #pragma unroll
                for (int r = 0; r < 16; ++r) {
                    int d = dg * 32 + (r & 3) + 8 * (r >> 2) + 4 * hi;
                    base[d * 32 + la] = o[dg][r];
                }
        }
        __syncthreads();
        {
            int m  = t & 31;
            int dq = (t >> 5) & 7;
            int jh = t >> 8;           // 0,1 : two jq each
            size_t gbase = ((size_t)(b * L_SEQ + mtile * 64 + p * 32 + m)) * DD + dq * 16;
            #pragma unroll
            for (int jj = 0; jj < 2; ++jj) {
                int jq = jh * 2 + jj;
                f32x4 v;
                #pragma unroll
                for (int e = 0; e < 4; ++e) {
                    int idx = (dq * 16 + jq * 4 + e) * 32 + m;
                    v[e] = red[0][idx] + red[1][idx] + red[2][idx] + red[3][idx];
                }
                f32x4 mv = *(const f32x4*)&mn[gbase + jq * 4];
                f32x4 ov;
                ov[0] = mv[0] - v[0]; ov[1] = mv[1] - v[1];
                ov[2] = mv[2] - v[2]; ov[3] = mv[3] - v[3];
                *(f32x4*)&out[gbase + jq * 4] = ov;
            }
        }
    }
}

// ---------------------------------------------------------------------------
// Fallback path (round-2 kernels, tiny workspace)
// ---------------------------------------------------------------------------

__global__ __launch_bounds__(256, 4) void stats_fb(const float* __restrict__ ctx,
                                                   const float* __restrict__ mn,
                                                   float* __restrict__ Lg) {
    __shared__ short Cs[64 * LDA];
    __shared__ short Ms[64 * LDA];

    int bid = blockIdx.x;
    int mc = bid & 3;
    int ct = (bid >> 2) & 31;
    int b  = bid >> 7;
    int t = threadIdx.x;
    int w = t >> 6;
    int l = t & 63;
    int a15 = l & 15;
    int q = l >> 4;

    stage_tile<256>(Cs, ctx + ((size_t)b * L_SEQ + ct * 64) * DD, 64 * DD, t);

    float ls[4] = {0.f, 0.f, 0.f, 0.f};
    for (int mt = 0; mt < 8; ++mt) {
        __syncthreads();
        int m0 = (mc * 8 + mt) * 64;
        stage_tile<256>(Ms, mn + ((size_t)b * L_SEQ + m0) * DD, 64 * DD, t);
        __syncthreads();

        f32x4 acc[4] = {{0.f,0.f,0.f,0.f},{0.f,0.f,0.f,0.f},{0.f,0.f,0.f,0.f},{0.f,0.f,0.f,0.f}};
        #pragma unroll
        for (int ks = 0; ks < 4; ++ks) {
            int k0 = ks * 32 + q * 8;
            bf16x8 a = *(const bf16x8*)&Cs[(w * 16 + a15) * LDA + k0];
            #pragma unroll
            for (int g = 0; g < 4; ++g) {
                bf16x8 bb = *(const bf16x8*)&Ms[(g * 16 + a15) * LDA + k0];
                acc[g] = __builtin_amdgcn_mfma_f32_16x16x32_bf16(a, bb, acc[g], 0, 0, 0);
            }
        }
        #pragma unroll
        for (int g = 0; g < 4; ++g)
            #pragma unroll
            for (int r = 0; r < 4; ++r)
                ls[r] += __expf(acc[g][r] - SHIFT);
    }

    #pragma unroll
    for (int r = 0; r < 4; ++r) {
        float v = ls[r];
        v += __shfl_xor(v, 1);
        v += __shfl_xor(v, 2);
        v += __shfl_xor(v, 4);
        v += __shfl_xor(v, 8);
        ls[r] = v;
    }
    if (a15 == 0) {
        int c = ct * 64 + w * 16 + q * 4;
        #pragma unroll
        for (int r = 0; r < 4; ++r)
            atomicAdd(&Lg[(size_t)b * L_SEQ + c + r], ls[r]);
    }
}

__global__ __launch_bounds__(1024, 4) void attend_fb(const float* __restrict__ ctx,
                                                     const float* __restrict__ mn,
                                                     const float* __restrict__ Lg,
                                                     float* __restrict__ out) {
    __shared__ short Mt[64 * LDA];
    __shared__ short Cs[128 * LDA];
    __shared__ short Ct[128 * LDA];
    __shared__ short Ps[64 * LDA];
    __shared__ float invLs[128];

    int bid = blockIdx.x;
    int mtile = bid & 31;
    int b = bid >> 5;
    int m0 = mtile * 64;
    int t = threadIdx.x;
    int w = t >> 6;
    int l = t & 63;
    int a15 = l & 15;
    int q = l >> 4;
    int mg = w & 3;
    int pg = w >> 2;

    stage_tile<1024>(Mt, mn + ((size_t)b * L_SEQ + m0) * DD, 64 * DD, t);

    f32x4 oacc[2] = {{0.f,0.f,0.f,0.f},{0.f,0.f,0.f,0.f}};

    for (int cs = 0; cs < 16; ++cs) {
        int c0 = cs * 128;
        __syncthreads();
        stage_tile<1024>(Cs, ctx + ((size_t)b * L_SEQ + c0) * DD, 128 * DD, t);
        if (t < 128) invLs[t] = 1.0f / Lg[(size_t)b * L_SEQ + c0 + t];
        __syncthreads();

        {
            int cc = t & 127;
            int d0 = (t >> 7) * 16;
            #pragma unroll
            for (int hh = 0; hh < 2; ++hh) {
                bf16x8 v = *(const bf16x8*)&Cs[cc * LDA + d0 + hh * 8];
                #pragma unroll
                for (int j = 0; j < 8; ++j)
                    Ct[(d0 + hh * 8 + j) * LDA + cc] = v[j];
            }
        }

        f32x4 sacc[2] = {{0.f,0.f,0.f,0.f},{0.f,0.f,0.f,0.f}};
        #pragma unroll
        for (int ks = 0; ks < 4; ++ks) {
            int k0 = ks * 32 + q * 8;
            bf16x8 a = *(const bf16x8*)&Mt[(mg * 16 + a15) * LDA + k0];
            #pragma unroll
            for (int g = 0; g < 2; ++g) {
                bf16x8 bb = *(const bf16x8*)&Cs[((pg * 2 + g) * 16 + a15) * LDA + k0];
                sacc[g] = __builtin_amdgcn_mfma_f32_16x16x32_bf16(a, bb, sacc[g], 0, 0, 0);
            }
        }
        #pragma unroll
        for (int g = 0; g < 2; ++g) {
            int cl = (pg * 2 + g) * 16 + a15;
            float il = invLs[cl];
            #pragma unroll
            for (int r = 0; r < 4; ++r) {
                float p = __expf(sacc[g][r] - SHIFT) * il;
                Ps[(mg * 16 + q * 4 + r) * LDA + cl] = f2bf(p);
            }
        }
        __syncthreads();

        #pragma unroll
        for (int ks = 0; ks < 4; ++ks) {
            int k0 = ks * 32 + q * 8;
            bf16x8 a = *(const bf16x8*)&Ps[(mg * 16 + a15) * LDA + k0];
            #pragma unroll
            for (int g = 0; g < 2; ++g) {
                bf16x8 bb = *(const bf16x8*)&Ct[((pg * 2 + g) * 16 + a15) * LDA + k0];
                oacc[g] = __builtin_amdgcn_mfma_f32_16x16x32_bf16(a, bb, oacc[g], 0, 0, 0);
            }
        }
    }

    #pragma unroll
    for (int g = 0; g < 2; ++g) {
        int dl = (pg * 2 + g) * 16 + a15;
        #pragma unroll
        for (int r = 0; r < 4; ++r) {
            int ml = mg * 16 + q * 4 + r;
            size_t idx = ((size_t)b * L_SEQ + m0 + ml) * DD + dl;
            out[idx] = mn[idx] - oacc[g][r];
        }
    }
}

// ---------------------------------------------------------------------------

extern "C" void kernel_launch(void* const* d_in, const int* in_sizes, int n_in,
                              void* d_out, int out_size, void* d_ws, size_t ws_size,
                              hipStream_t stream) {
    const float* ctx = (const float*)d_in[0];  // (B, Lc, D)
    const float* mn  = (const float*)d_in[1];  // (B, Lm, D)
    float* out = (float*)d_out;                // (B, Lm, D)

    // Workspace: invLg 64 KB | Cf 4 MB | Mf 4 MB | Ctf 4 MB
    const size_t LG_BYTES = (size_t)BATCH * L_SEQ * sizeof(float);
    const size_t BF_BYTES = (size_t)BATCH * L_SEQ * DD * sizeof(short);
    const size_t NEED = LG_BYTES + 3 * BF_BYTES;

    float* Lg = (float*)d_ws;

    if (ws_size >= NEED) {
        short* Cf  = (short*)((char*)d_ws + LG_BYTES);
        short* Mf  = (short*)((char*)d_ws + LG_BYTES + BF_BYTES);
        short* Ctf = (short*)((char*)d_ws + LG_BYTES + 2 * BF_BYTES);
        convert_kernel<<<1024, 256, 0, stream>>>(ctx, mn, Cf, Mf, Ctf);
        stats_kernel<<<256, 512, 0, stream>>>(Cf, Mf, Lg);
        attend_fused<<<256, 512, 0, stream>>>(Cf, Mf, Ctf, Lg, mn, out);
    } else {
        int nL = BATCH * L_SEQ;
        zero_kernel<<<(nL + 255) / 256, 256, 0, stream>>>(Lg, nL);
        stats_fb<<<BATCH * 32 * 4, 256, 0, stream>>>(ctx, mn, Lg);
        attend_fb<<<BATCH * 32, 1024, 0, stream>>>(ctx, mn, Lg, out);
    }
}

// Round 10
// 118.455 us; speedup vs baseline: 1.2633x; 1.2633x over previous
//
#include <hip/hip_runtime.h>

// AlignOnlySubLayer: out[b,m,d] = main[b,m,d] - sum_c softmax_m(C·M^T)[c,m] * C[c,d]
// B=8, Lc=Lm=2048, D=128, fp32 in/out.
// Round-19: REVERT attend to the R17-proven m-tile-32 shape (R18's m-tile-64
// regressed 3x: VGPR demotion/spill + 1 monolithic block/CU lost block-level
// overlap). Single change on top: s_setprio(1) around attend's MFMA clusters
// (T5 — attend's main loop is barrier-free, waves drift into different
// phases, the regime where setprio pays).
// convert/stats: R17 bodies verbatim.
// Record layouts (la=l&31, hi=l>>5, e=0..7):
//   Cf [((b*16+cs)*4+ch)*8+ks]          lane l = C[cs*128+ch*32+la][(ks*2+hi)*8+e]
//   Mf [(b*64+mw)*8+ks]                 lane l = M[mw*32+la][(ks*2+hi)*8+e]
//   Ctf[(((b*16+cs)*4+ch)*4+dg)*2+ks2]  lane l = C[cs*128+(ch*4+ks2*2+hi)*8+e][dg*32+la]
// MFMA frag layout (32x32x16, verified R9-R17): A/B lane (la,hi) holds
// row/col la, k = hi*8+e; D: col=la, row=(r&3)+8*(r>>2)+4*hi.

#define BATCH 8
#define L_SEQ 2048
#define DD 128
#define SHIFT 40.0f
#define LDA 136   // fallback padded stride
#define TLD 136   // convert LDS tile stride (shorts)

typedef __attribute__((ext_vector_type(8))) short bf16x8;
typedef __attribute__((ext_vector_type(4))) float f32x4;
typedef __attribute__((ext_vector_type(16))) float f32x16;
typedef __attribute__((ext_vector_type(4))) unsigned int uint4v;

__device__ __forceinline__ short f2bf(float f) {
    unsigned u = __builtin_bit_cast(unsigned, f);
    return (short)((u + 0x8000u) >> 16);
}

// fp32 global (rows of 128) -> bf16 LDS tile, stride LDA (fallback path only).
template <int NT>
__device__ __forceinline__ void stage_tile(short* __restrict__ dst,
                                           const float* __restrict__ src,
                                           int nelts, int t) {
    for (int base = 0; base < nelts; base += NT * 8) {
        int flat = base + t * 8;
        const float4* p = (const float4*)(src + flat);
        float4 v0 = p[0];
        float4 v1 = p[1];
        bf16x8 s;
        s[0] = f2bf(v0.x); s[1] = f2bf(v0.y); s[2] = f2bf(v0.z); s[3] = f2bf(v0.w);
        s[4] = f2bf(v1.x); s[5] = f2bf(v1.y); s[6] = f2bf(v1.z); s[7] = f2bf(v1.w);
        int row = flat >> 7;
        int col = flat & 127;
        *(bf16x8*)&dst[row * LDA + col] = s;
    }
}

__global__ __launch_bounds__(256) void zero_kernel(float* __restrict__ p, int n) {
    int i = blockIdx.x * 256 + threadIdx.x;
    if (i < n) p[i] = 0.0f;
}

// ---------------------------------------------------------------------------
// Fast path
// ---------------------------------------------------------------------------

// grid = 2 tensors x 8 b x 64 rowgroups = 1024 blocks, 256 thr.
// Stages a 32-row fp32 tile -> bf16 LDS, then emits fragment records.
__global__ __launch_bounds__(256) void convert_kernel(const float* __restrict__ ctx,
                                                      const float* __restrict__ mn,
                                                      short* __restrict__ Cf,
                                                      short* __restrict__ Mf,
                                                      short* __restrict__ Ctf) {
    __shared__ short Ts[32 * TLD];

    int bid = blockIdx.x;
    int tsel = bid & 1;
    int b = (bid >> 1) & 7;
    int rg = bid >> 4;          // 0..63 : 32-row group
    int t = threadIdx.x;

    const float* src = (tsel ? mn : ctx) + ((size_t)(b * L_SEQ + rg * 32)) * DD;

    #pragma unroll
    for (int i = 0; i < 2; ++i) {
        int flat = i * 2048 + t * 8;
        int r = flat >> 7;
        int d = flat & 127;
        const float4* p = (const float4*)(src + flat);
        float4 v0 = p[0];
        float4 v1 = p[1];
        bf16x8 s;
        s[0] = f2bf(v0.x); s[1] = f2bf(v0.y); s[2] = f2bf(v0.z); s[3] = f2bf(v0.w);
        s[4] = f2bf(v1.x); s[5] = f2bf(v1.y); s[6] = f2bf(v1.z); s[7] = f2bf(v1.w);
        *(bf16x8*)&Ts[r * TLD + d] = s;
    }
    __syncthreads();

    if (tsel == 0) {
        int cs = rg >> 2;
        int ch = rg & 3;
        // Cf: 8 records (ks), 64 lane-slots each; 2 slots/thread.
        size_t cfb = (size_t)(((b * 16 + cs) * 4 + ch) * 8) * 512;
        #pragma unroll
        for (int i = 0; i < 2; ++i) {
            int slot = i * 256 + t;
            int ks = slot >> 6;
            int l2 = slot & 63;
            int la = l2 & 31;
            int hi = l2 >> 5;
            bf16x8 v = *(const bf16x8*)&Ts[la * TLD + (ks * 2 + hi) * 8];
            *(bf16x8*)&Cf[cfb + (size_t)ks * 512 + l2 * 8] = v;
        }
        // Ctf: 8 records (dg,ks2); transpose gather from LDS.
        size_t ctb = (size_t)((((b * 16 + cs) * 4 + ch) * 4) * 2) * 512;
        #pragma unroll
        for (int i = 0; i < 2; ++i) {
            int slot = i * 256 + t;
            int recl = slot >> 6;       // dg*2 + ks2
            int l2 = slot & 63;
            int dg = recl >> 1;
            int ks2 = recl & 1;
            int la = l2 & 31;
            int hi = l2 >> 5;
            int d = dg * 32 + la;
            int c0 = (ks2 * 2 + hi) * 8;     // local c row base
            bf16x8 v;
            #pragma unroll
            for (int j = 0; j < 8; ++j) v[j] = Ts[(c0 + j) * TLD + d];
            *(bf16x8*)&Ctf[ctb + (size_t)recl * 512 + l2 * 8] = v;
        }
    } else {
        // Mf: 8 records (ks); rowgroup rg = mw.
        size_t mfb = (size_t)((b * 64 + rg) * 8) * 512;
        #pragma unroll
        for (int i = 0; i < 2; ++i) {
            int slot = i * 256 + t;
            int ks = slot >> 6;
            int l2 = slot & 63;
            int la = l2 & 31;
            int hi = l2 >> 5;
            bf16x8 v = *(const bf16x8*)&Ts[la * TLD + (ks * 2 + hi) * 8];
            *(bf16x8*)&Mf[mfb + (size_t)ks * 512 + l2 * 8] = v;
        }
    }
}

// grid = 8 b x 32 ct2(64 c) = 256 blocks (b = bid&7), 512 thr (8 waves).
// Swapped S: D[i=m][j=c=la] = mfma(Mf, Cf). c-tile 64: cf[2][8] hoisted,
// TWO independent accumulator chains per Mf load. Writes invL directly.
__global__ __launch_bounds__(512) void stats_kernel(const short* __restrict__ Cf,
                                                    const short* __restrict__ Mf,
                                                    float* __restrict__ invLg) {
    __shared__ float red[8][2][32];

    int bid = blockIdx.x;
    int b = bid & 7;
    int ct2 = bid >> 3;         // 0..31 : 64-c tile
    int t = threadIdx.x;
    int w = t >> 6;             // 0..7
    int l = t & 63;
    int la = l & 31;

    // Hoist C B-frags for the two 32-c subtiles (ct = ct2*2 + j).
    bf16x8 cf[2][8];
    #pragma unroll
    for (int j = 0; j < 2; ++j) {
        int ct = ct2 * 2 + j;
        const short* cfp = Cf + (size_t)(((b * 16 + (ct >> 2)) * 4 + (ct & 3)) * 8) * 512 + l * 8;
        #pragma unroll
        for (int ks = 0; ks < 8; ++ks)
            cf[j][ks] = *(const bf16x8*)&cfp[(size_t)ks * 512];
    }

    float lacc0 = 0.0f, lacc1 = 0.0f;
    for (int i = 0; i < 8; ++i) {
        int mw = w * 8 + i;
        const short* mfp = Mf + (size_t)((b * 64 + mw) * 8) * 512 + l * 8;
        f32x16 s0, s1;
        #pragma unroll
        for (int r = 0; r < 16; ++r) { s0[r] = 0.0f; s1[r] = 0.0f; }
        #pragma unroll
        for (int ks = 0; ks < 8; ++ks) {
            bf16x8 av = *(const bf16x8*)&mfp[(size_t)ks * 512];
            s0 = __builtin_amdgcn_mfma_f32_32x32x16_bf16(av, cf[0][ks], s0, 0, 0, 0);
            s1 = __builtin_amdgcn_mfma_f32_32x32x16_bf16(av, cf[1][ks], s1, 0, 0, 0);
        }
        #pragma unroll
        for (int r = 0; r < 16; ++r) {
            lacc0 += __expf(s0[r] - SHIFT);
            lacc1 += __expf(s1[r] - SHIFT);
        }
    }

    // lanes l and l+32 hold the same c (col=la), disjoint m rows: combine,
    // then reduce the 8 waves through 2 KB LDS.
    lacc0 += __shfl_xor(lacc0, 32);
    lacc1 += __shfl_xor(lacc1, 32);
    if (l < 32) { red[w][0][la] = lacc0; red[w][1][la] = lacc1; }
    __syncthreads();
    if (t < 64) {
        int j = t >> 5;
        int c = t & 31;
        float L = 0.0f;
        #pragma unroll
        for (int ww = 0; ww < 8; ++ww) L += red[ww][j][c];
        invLg[(size_t)b * L_SEQ + ct2 * 64 + j * 32 + c] = 1.0f / L;
    }
}

// grid = 8 b x 64 mtiles(32 m) = 512 blocks (b = bid&7), 256 thr = 4 waves
// (4 c-slices). ALL operands are coalesced records; NO barriers in the main
// loop. LDS 64 KB only for the epilogue cross-slice reduction (2 blocks/CU).
// setprio(1) around the MFMA clusters (T5: barrier-free waves drift, the
// scheduler can prefer MFMA-entering waves).
__global__ __launch_bounds__(256, 2) void attend_fused(const short* __restrict__ Cf,
                                                       const short* __restrict__ Mf,
                                                       const short* __restrict__ Ctf,
                                                       const float* __restrict__ invLg,
                                                       const float* __restrict__ mn,
                                                       float* __restrict__ out) {
    __shared__ float red[4][4096];

    int bid = blockIdx.x;
    int b = bid & 7;
    int mtile = bid >> 3;       // 0..63
    int t = threadIdx.x;
    int w = t >> 6;             // ch
    int l = t & 63;
    int la = l & 31;
    int hi = l >> 5;
    int ch = w;

    // Hoist M B-frags from Mf record (mw = mtile) — same records stats read.
    bf16x8 mf[8];
    {
        const short* mfp = Mf + (size_t)((b * 64 + mtile) * 8) * 512 + l * 8;
        #pragma unroll
        for (int ks = 0; ks < 8; ++ks)
            mf[ks] = *(const bf16x8*)&mfp[(size_t)ks * 512];
    }

    f32x16 o[4];
    #pragma unroll
    for (int dg = 0; dg < 4; ++dg)
        #pragma unroll
        for (int r = 0; r < 16; ++r) o[dg][r] = 0.0f;

    const float* ilbase = invLg + (size_t)b * L_SEQ + ch * 32 + hi * 4;

    for (int cs = 0; cs < 16; ++cs) {
        const short* cfp = Cf + (size_t)(((b * 16 + cs) * 4 + ch) * 8) * 512 + l * 8;
        const short* tfp = Ctf + (size_t)((((b * 16 + cs) * 4 + ch) * 4) * 2) * 512 + l * 8;

        // PV A-frags: 8 coalesced record loads (independent of S, fly early).
        bf16x8 tv[4][2];
        #pragma unroll
        for (int dg = 0; dg < 4; ++dg)
            #pragma unroll
            for (int ks2 = 0; ks2 < 2; ++ks2)
                tv[dg][ks2] = *(const bf16x8*)&tfp[(size_t)(dg * 2 + ks2) * 512];

        // invL for this window's 16 c's per lane (broadcast float4 loads).
        f32x4 ilv[4];
        #pragma unroll
        for (int q = 0; q < 4; ++q)
            ilv[q] = *(const f32x4*)&ilbase[cs * 128 + q * 8];

        // S-GEMM (swapped): D[i=c][j=m=la], A = Cf records.
        f32x16 s;
        #pragma unroll
        for (int r = 0; r < 16; ++r) s[r] = 0.0f;
        __builtin_amdgcn_s_setprio(1);
        #pragma unroll
        for (int ks = 0; ks < 8; ++ks) {
            bf16x8 av = *(const bf16x8*)&cfp[(size_t)ks * 512];
            s = __builtin_amdgcn_mfma_f32_32x32x16_bf16(av, mf[ks], s, 0, 0, 0);
        }
        __builtin_amdgcn_s_setprio(0);

        // P = exp(S-40) * invL[c] -> bf16 pairs. reg r=q*4+sub: c_local = sub+8q+4hi.
        unsigned u[4][2];
        #pragma unroll
        for (int q = 0; q < 4; ++q)
            #pragma unroll
            for (int jj = 0; jj < 2; ++jj) {
                float e0 = __expf(s[q * 4 + jj * 2]     - SHIFT) * ilv[q][jj * 2];
                float e1 = __expf(s[q * 4 + jj * 2 + 1] - SHIFT) * ilv[q][jj * 2 + 1];
                u[q][jj] = ((unsigned)(unsigned short)f2bf(e1) << 16)
                         |  (unsigned)(unsigned short)f2bf(e0);
            }

        // Half-wave exchange -> PV B-frags (c_local = ks2*16 + hi*8 + 0..7).
        bf16x8 pa[2];
        #pragma unroll
        for (int ks2 = 0; ks2 < 2; ++ks2) {
            unsigned a0 = u[2 * ks2][0],     a1 = u[2 * ks2][1];
            unsigned b0 = u[2 * ks2 + 1][0], b1 = u[2 * ks2 + 1][1];
            unsigned a0p = (unsigned)__shfl_xor((int)a0, 32);
            unsigned a1p = (unsigned)__shfl_xor((int)a1, 32);
            unsigned b0p = (unsigned)__shfl_xor((int)b0, 32);
            unsigned b1p = (unsigned)__shfl_xor((int)b1, 32);
            uint4v pw;
            pw.x = hi ? b0p : a0;
            pw.y = hi ? b1p : a1;
            pw.z = hi ? b0  : a0p;
            pw.w = hi ? b1  : a1p;
            pa[ks2] = __builtin_bit_cast(bf16x8, pw);
        }

        // PV: D2[i=d][j=m], A = tv (Ctf records), B = pa.
        __builtin_amdgcn_s_setprio(1);
        #pragma unroll
        for (int dg = 0; dg < 4; ++dg)
            #pragma unroll
            for (int ks2 = 0; ks2 < 2; ++ks2)
                o[dg] = __builtin_amdgcn_mfma_f32_32x32x16_bf16(tv[dg][ks2], pa[ks2], o[dg], 0, 0, 0);
        __builtin_amdgcn_s_setprio(0);
    }

    // Epilogue: per-wave partials -> LDS, sum 4 c-slices, out = main - sum.
    {
        float* base = red[w];
        #pragma unroll
        for (int dg = 0; dg < 4; ++dg)
            #pragma unroll
            for (int r = 0; r < 16; ++r) {
                int d = dg * 32 + (r & 3) + 8 * (r >> 2) + 4 * hi;
                base[d * 32 + la] = o[dg][r];
            }
    }
    __syncthreads();

    {
        int m  = t & 31;
        int dq = t >> 5;
        size_t gbase = ((size_t)(b * L_SEQ + mtile * 32 + m)) * DD + dq * 16;
        #pragma unroll
        for (int jq = 0; jq < 4; ++jq) {
            f32x4 v;
            #pragma unroll
            for (int e = 0; e < 4; ++e) {
                int idx = (dq * 16 + jq * 4 + e) * 32 + m;
                v[e] = red[0][idx] + red[1][idx] + red[2][idx] + red[3][idx];
            }
            f32x4 mv = *(const f32x4*)&mn[gbase + jq * 4];
            f32x4 ov;
            ov[0] = mv[0] - v[0]; ov[1] = mv[1] - v[1];
            ov[2] = mv[2] - v[2]; ov[3] = mv[3] - v[3];
            *(f32x4*)&out[gbase + jq * 4] = ov;
        }
    }
}

// ---------------------------------------------------------------------------
// Fallback path (round-2 kernels, tiny workspace)
// ---------------------------------------------------------------------------

__global__ __launch_bounds__(256, 4) void stats_fb(const float* __restrict__ ctx,
                                                   const float* __restrict__ mn,
                                                   float* __restrict__ Lg) {
    __shared__ short Cs[64 * LDA];
    __shared__ short Ms[64 * LDA];

    int bid = blockIdx.x;
    int mc = bid & 3;
    int ct = (bid >> 2) & 31;
    int b  = bid >> 7;
    int t = threadIdx.x;
    int w = t >> 6;
    int l = t & 63;
    int a15 = l & 15;
    int q = l >> 4;

    stage_tile<256>(Cs, ctx + ((size_t)b * L_SEQ + ct * 64) * DD, 64 * DD, t);

    float ls[4] = {0.f, 0.f, 0.f, 0.f};
    for (int mt = 0; mt < 8; ++mt) {
        __syncthreads();
        int m0 = (mc * 8 + mt) * 64;
        stage_tile<256>(Ms, mn + ((size_t)b * L_SEQ + m0) * DD, 64 * DD, t);
        __syncthreads();

        f32x4 acc[4] = {{0.f,0.f,0.f,0.f},{0.f,0.f,0.f,0.f},{0.f,0.f,0.f,0.f},{0.f,0.f,0.f,0.f}};
        #pragma unroll
        for (int ks = 0; ks < 4; ++ks) {
            int k0 = ks * 32 + q * 8;
            bf16x8 a = *(const bf16x8*)&Cs[(w * 16 + a15) * LDA + k0];
            #pragma unroll
            for (int g = 0; g < 4; ++g) {
                bf16x8 bb = *(const bf16x8*)&Ms[(g * 16 + a15) * LDA + k0];
                acc[g] = __builtin_amdgcn_mfma_f32_16x16x32_bf16(a, bb, acc[g], 0, 0, 0);
            }
        }
        #pragma unroll
        for (int g = 0; g < 4; ++g)
            #pragma unroll
            for (int r = 0; r < 4; ++r)
                ls[r] += __expf(acc[g][r] - SHIFT);
    }

    #pragma unroll
    for (int r = 0; r < 4; ++r) {
        float v = ls[r];
        v += __shfl_xor(v, 1);
        v += __shfl_xor(v, 2);
        v += __shfl_xor(v, 4);
        v += __shfl_xor(v, 8);
        ls[r] = v;
    }
    if (a15 == 0) {
        int c = ct * 64 + w * 16 + q * 4;
        #pragma unroll
        for (int r = 0; r < 4; ++r)
            atomicAdd(&Lg[(size_t)b * L_SEQ + c + r], ls[r]);
    }
}

__global__ __launch_bounds__(1024, 4) void attend_fb(const float* __restrict__ ctx,
                                                     const float* __restrict__ mn,
                                                     const float* __restrict__ Lg,
                                                     float* __restrict__ out) {
    __shared__ short Mt[64 * LDA];
    __shared__ short Cs[128 * LDA];
    __shared__ short Ct[128 * LDA];
    __shared__ short Ps[64 * LDA];
    __shared__ float invLs[128];

    int bid = blockIdx.x;
    int mtile = bid & 31;
    int b = bid >> 5;
    int m0 = mtile * 64;
    int t = threadIdx.x;
    int w = t >> 6;
    int l = t & 63;
    int a15 = l & 15;
    int q = l >> 4;
    int mg = w & 3;
    int pg = w >> 2;

    stage_tile<1024>(Mt, mn + ((size_t)b * L_SEQ + m0) * DD, 64 * DD, t);

    f32x4 oacc[2] = {{0.f,0.f,0.f,0.f},{0.f,0.f,0.f,0.f}};

    for (int cs = 0; cs < 16; ++cs) {
        int c0 = cs * 128;
        __syncthreads();
        stage_tile<1024>(Cs, ctx + ((size_t)b * L_SEQ + c0) * DD, 128 * DD, t);
        if (t < 128) invLs[t] = 1.0f / Lg[(size_t)b * L_SEQ + c0 + t];
        __syncthreads();

        {
            int cc = t & 127;
            int d0 = (t >> 7) * 16;
            #pragma unroll
            for (int hh = 0; hh < 2; ++hh) {
                bf16x8 v = *(const bf16x8*)&Cs[cc * LDA + d0 + hh * 8];
                #pragma unroll
                for (int j = 0; j < 8; ++j)
                    Ct[(d0 + hh * 8 + j) * LDA + cc] = v[j];
            }
        }

        f32x4 sacc[2] = {{0.f,0.f,0.f,0.f},{0.f,0.f,0.f,0.f}};
        #pragma unroll
        for (int ks = 0; ks < 4; ++ks) {
            int k0 = ks * 32 + q * 8;
            bf16x8 a = *(const bf16x8*)&Mt[(mg * 16 + a15) * LDA + k0];
            #pragma unroll
            for (int g = 0; g < 2; ++g) {
                bf16x8 bb = *(const bf16x8*)&Cs[((pg * 2 + g) * 16 + a15) * LDA + k0];
                sacc[g] = __builtin_amdgcn_mfma_f32_16x16x32_bf16(a, bb, sacc[g], 0, 0, 0);
            }
        }
        #pragma unroll
        for (int g = 0; g < 2; ++g) {
            int cl = (pg * 2 + g) * 16 + a15;
            float il = invLs[cl];
            #pragma unroll
            for (int r = 0; r < 4; ++r) {
                float p = __expf(sacc[g][r] - SHIFT) * il;
                Ps[(mg * 16 + q * 4 + r) * LDA + cl] = f2bf(p);
            }
        }
        __syncthreads();

        #pragma unroll
        for (int ks = 0; ks < 4; ++ks) {
            int k0 = ks * 32 + q * 8;
            bf16x8 a = *(const bf16x8*)&Ps[(mg * 16 + a15) * LDA + k0];
            #pragma unroll
            for (int g = 0; g < 2; ++g) {
                bf16x8 bb = *(const bf16x8*)&Ct[((pg * 2 + g) * 16 + a15) * LDA + k0];
                oacc[g] = __builtin_amdgcn_mfma_f32_16x16x32_bf16(a, bb, oacc[g], 0, 0, 0);
            }
        }
    }

    #pragma unroll
    for (int g = 0; g < 2; ++g) {
        int dl = (pg * 2 + g) * 16 + a15;
        #pragma unroll
        for (int r = 0; r < 4; ++r) {
            int ml = mg * 16 + q * 4 + r;
            size_t idx = ((size_t)b * L_SEQ + m0 + ml) * DD + dl;
            out[idx] = mn[idx] - oacc[g][r];
        }
    }
}

// ---------------------------------------------------------------------------

extern "C" void kernel_launch(void* const* d_in, const int* in_sizes, int n_in,
                              void* d_out, int out_size, void* d_ws, size_t ws_size,
                              hipStream_t stream) {
    const float* ctx = (const float*)d_in[0];  // (B, Lc, D)
    const float* mn  = (const float*)d_in[1];  // (B, Lm, D)
    float* out = (float*)d_out;                // (B, Lm, D)

    // Workspace: invLg 64 KB | Cf 4 MB | Mf 4 MB | Ctf 4 MB
    const size_t LG_BYTES = (size_t)BATCH * L_SEQ * sizeof(float);
    const size_t BF_BYTES = (size_t)BATCH * L_SEQ * DD * sizeof(short);
    const size_t NEED = LG_BYTES + 3 * BF_BYTES;

    float* Lg = (float*)d_ws;

    if (ws_size >= NEED) {
        short* Cf  = (short*)((char*)d_ws + LG_BYTES);
        short* Mf  = (short*)((char*)d_ws + LG_BYTES + BF_BYTES);
        short* Ctf = (short*)((char*)d_ws + LG_BYTES + 2 * BF_BYTES);
        convert_kernel<<<1024, 256, 0, stream>>>(ctx, mn, Cf, Mf, Ctf);
        stats_kernel<<<256, 512, 0, stream>>>(Cf, Mf, Lg);
        attend_fused<<<512, 256, 0, stream>>>(Cf, Mf, Ctf, Lg, mn, out);
    } else {
        int nL = BATCH * L_SEQ;
        zero_kernel<<<(nL + 255) / 256, 256, 0, stream>>>(Lg, nL);
        stats_fb<<<BATCH * 32 * 4, 256, 0, stream>>>(ctx, mn, Lg);
        attend_fb<<<BATCH * 32, 1024, 0, stream>>>(ctx, mn, Lg, out);
    }
}

// Round 11
// 112.695 us; speedup vs baseline: 1.3279x; 1.0511x over previous
//
#include <hip/hip_runtime.h>

// AlignOnlySubLayer: out[b,m,d] = main[b,m,d] - sum_c softmax_m(C·M^T)[c,m] * C[c,d]
// B=8, Lc=Lm=2048, D=128, fp32 in/out.
// Round-20: stats c-tile 128 via m-split + atomics. R19's setprio was neutral/
// negative -> dropped (back to R17 attend). stats' 512 MB Mf stream was
// geometry-locked only by invL needing complete L; with atomicAdd-L (2 adds
// per address) we run 8b x 16ct4 x 2ms = 256 blocks (1/CU), each hoisting
// cf[4][8] (4 MFMA chains/load, 2x R17 ILP) and streaming HALF the Mf panel
// -> 256 MB total (-50%). convert zeroes Lg; attend computes invL with
// v_rcp_f32 on the fly (~1e-7 rel, invisible at absmax tolerance).
// Record layouts (la=l&31, hi=l>>5, e=0..7):
//   Cf [((b*16+cs)*4+ch)*8+ks]          lane l = C[cs*128+ch*32+la][(ks*2+hi)*8+e]
//   Mf [(b*64+mw)*8+ks]                 lane l = M[mw*32+la][(ks*2+hi)*8+e]
//   Ctf[(((b*16+cs)*4+ch)*4+dg)*2+ks2]  lane l = C[cs*128+(ch*4+ks2*2+hi)*8+e][dg*32+la]
// MFMA frag layout (32x32x16, verified R9-R17): A/B lane (la,hi) holds
// row/col la, k = hi*8+e; D: col=la, row=(r&3)+8*(r>>2)+4*hi.

#define BATCH 8
#define L_SEQ 2048
#define DD 128
#define SHIFT 40.0f
#define LDA 136   // fallback padded stride
#define TLD 136   // convert LDS tile stride (shorts)

typedef __attribute__((ext_vector_type(8))) short bf16x8;
typedef __attribute__((ext_vector_type(4))) float f32x4;
typedef __attribute__((ext_vector_type(16))) float f32x16;
typedef __attribute__((ext_vector_type(4))) unsigned int uint4v;

__device__ __forceinline__ short f2bf(float f) {
    unsigned u = __builtin_bit_cast(unsigned, f);
    return (short)((u + 0x8000u) >> 16);
}

// fp32 global (rows of 128) -> bf16 LDS tile, stride LDA (fallback path only).
template <int NT>
__device__ __forceinline__ void stage_tile(short* __restrict__ dst,
                                           const float* __restrict__ src,
                                           int nelts, int t) {
    for (int base = 0; base < nelts; base += NT * 8) {
        int flat = base + t * 8;
        const float4* p = (const float4*)(src + flat);
        float4 v0 = p[0];
        float4 v1 = p[1];
        bf16x8 s;
        s[0] = f2bf(v0.x); s[1] = f2bf(v0.y); s[2] = f2bf(v0.z); s[3] = f2bf(v0.w);
        s[4] = f2bf(v1.x); s[5] = f2bf(v1.y); s[6] = f2bf(v1.z); s[7] = f2bf(v1.w);
        int row = flat >> 7;
        int col = flat & 127;
        *(bf16x8*)&dst[row * LDA + col] = s;
    }
}

__global__ __launch_bounds__(256) void zero_kernel(float* __restrict__ p, int n) {
    int i = blockIdx.x * 256 + threadIdx.x;
    if (i < n) p[i] = 0.0f;
}

// ---------------------------------------------------------------------------
// Fast path
// ---------------------------------------------------------------------------

// grid = 2 tensors x 8 b x 64 rowgroups = 1024 blocks, 256 thr.
// Stages a 32-row fp32 tile -> bf16 LDS, emits fragment records; zeroes Lg.
__global__ __launch_bounds__(256) void convert_kernel(const float* __restrict__ ctx,
                                                      const float* __restrict__ mn,
                                                      short* __restrict__ Cf,
                                                      short* __restrict__ Mf,
                                                      short* __restrict__ Ctf,
                                                      float* __restrict__ Lg) {
    __shared__ short Ts[32 * TLD];

    int bid = blockIdx.x;
    int tsel = bid & 1;
    int b = (bid >> 1) & 7;
    int rg = bid >> 4;          // 0..63 : 32-row group
    int t = threadIdx.x;

    {   // zero Lg (16384 floats; grid covers 262144 threads)
        int tid = bid * 256 + t;
        if (tid < BATCH * L_SEQ) Lg[tid] = 0.0f;
    }

    const float* src = (tsel ? mn : ctx) + ((size_t)(b * L_SEQ + rg * 32)) * DD;

    #pragma unroll
    for (int i = 0; i < 2; ++i) {
        int flat = i * 2048 + t * 8;
        int r = flat >> 7;
        int d = flat & 127;
        const float4* p = (const float4*)(src + flat);
        float4 v0 = p[0];
        float4 v1 = p[1];
        bf16x8 s;
        s[0] = f2bf(v0.x); s[1] = f2bf(v0.y); s[2] = f2bf(v0.z); s[3] = f2bf(v0.w);
        s[4] = f2bf(v1.x); s[5] = f2bf(v1.y); s[6] = f2bf(v1.z); s[7] = f2bf(v1.w);
        *(bf16x8*)&Ts[r * TLD + d] = s;
    }
    __syncthreads();

    if (tsel == 0) {
        int cs = rg >> 2;
        int ch = rg & 3;
        // Cf: 8 records (ks), 64 lane-slots each; 2 slots/thread.
        size_t cfb = (size_t)(((b * 16 + cs) * 4 + ch) * 8) * 512;
        #pragma unroll
        for (int i = 0; i < 2; ++i) {
            int slot = i * 256 + t;
            int ks = slot >> 6;
            int l2 = slot & 63;
            int la = l2 & 31;
            int hi = l2 >> 5;
            bf16x8 v = *(const bf16x8*)&Ts[la * TLD + (ks * 2 + hi) * 8];
            *(bf16x8*)&Cf[cfb + (size_t)ks * 512 + l2 * 8] = v;
        }
        // Ctf: 8 records (dg,ks2); transpose gather from LDS.
        size_t ctb = (size_t)((((b * 16 + cs) * 4 + ch) * 4) * 2) * 512;
        #pragma unroll
        for (int i = 0; i < 2; ++i) {
            int slot = i * 256 + t;
            int recl = slot >> 6;       // dg*2 + ks2
            int l2 = slot & 63;
            int dg = recl >> 1;
            int ks2 = recl & 1;
            int la = l2 & 31;
            int hi = l2 >> 5;
            int d = dg * 32 + la;
            int c0 = (ks2 * 2 + hi) * 8;     // local c row base
            bf16x8 v;
            #pragma unroll
            for (int j = 0; j < 8; ++j) v[j] = Ts[(c0 + j) * TLD + d];
            *(bf16x8*)&Ctf[ctb + (size_t)recl * 512 + l2 * 8] = v;
        }
    } else {
        // Mf: 8 records (ks); rowgroup rg = mw.
        size_t mfb = (size_t)((b * 64 + rg) * 8) * 512;
        #pragma unroll
        for (int i = 0; i < 2; ++i) {
            int slot = i * 256 + t;
            int ks = slot >> 6;
            int l2 = slot & 63;
            int la = l2 & 31;
            int hi = l2 >> 5;
            bf16x8 v = *(const bf16x8*)&Ts[la * TLD + (ks * 2 + hi) * 8];
            *(bf16x8*)&Mf[mfb + (size_t)ks * 512 + l2 * 8] = v;
        }
    }
}

// grid = 8 b x 16 ct4(128 c) x 2 msplit = 256 blocks (b = bid&7), 512 thr
// (8 waves, 1 block/CU). Swapped S: D[i=m][j=c=la] = mfma(Mf, Cf).
// cf[4][8] hoisted (128 VGPR), FOUR independent accumulator chains per Mf
// load; each block streams half the Mf panel (1 MB) -> 256 MB total.
// Partial L accumulated to Lg via atomicAdd (2 adds/address).
__global__ __launch_bounds__(512) void stats_kernel(const short* __restrict__ Cf,
                                                    const short* __restrict__ Mf,
                                                    float* __restrict__ Lg) {
    __shared__ float red[8][4][32];

    int bid = blockIdx.x;
    int b = bid & 7;
    int r2 = bid >> 3;
    int ct4 = r2 & 15;          // 128-c tile
    int ms = r2 >> 4;           // 0,1 : m half
    int t = threadIdx.x;
    int w = t >> 6;             // 0..7
    int l = t & 63;
    int la = l & 31;

    // Hoist C B-frags for the four 32-c subtiles (c = ct4*128 + j*32 + la).
    bf16x8 cf[4][8];
    #pragma unroll
    for (int j = 0; j < 4; ++j) {
        const short* cfp = Cf + (size_t)(((b * 16 + ct4) * 4 + j) * 8) * 512 + l * 8;
        #pragma unroll
        for (int ks = 0; ks < 8; ++ks)
            cf[j][ks] = *(const bf16x8*)&cfp[(size_t)ks * 512];
    }

    float lacc[4] = {0.f, 0.f, 0.f, 0.f};
    for (int i = 0; i < 4; ++i) {
        int mw = ms * 32 + w * 4 + i;
        const short* mfp = Mf + (size_t)((b * 64 + mw) * 8) * 512 + l * 8;
        f32x16 s0, s1, s2, s3;
        #pragma unroll
        for (int r = 0; r < 16; ++r) { s0[r] = 0.f; s1[r] = 0.f; s2[r] = 0.f; s3[r] = 0.f; }
        #pragma unroll
        for (int ks = 0; ks < 8; ++ks) {
            bf16x8 av = *(const bf16x8*)&mfp[(size_t)ks * 512];
            s0 = __builtin_amdgcn_mfma_f32_32x32x16_bf16(av, cf[0][ks], s0, 0, 0, 0);
            s1 = __builtin_amdgcn_mfma_f32_32x32x16_bf16(av, cf[1][ks], s1, 0, 0, 0);
            s2 = __builtin_amdgcn_mfma_f32_32x32x16_bf16(av, cf[2][ks], s2, 0, 0, 0);
            s3 = __builtin_amdgcn_mfma_f32_32x32x16_bf16(av, cf[3][ks], s3, 0, 0, 0);
        }
        #pragma unroll
        for (int r = 0; r < 16; ++r) {
            lacc[0] += __expf(s0[r] - SHIFT);
            lacc[1] += __expf(s1[r] - SHIFT);
            lacc[2] += __expf(s2[r] - SHIFT);
            lacc[3] += __expf(s3[r] - SHIFT);
        }
    }

    // lanes l and l+32 hold the same c (col=la), disjoint m rows: combine,
    // reduce the 8 waves through 4 KB LDS, one atomicAdd per (c).
    #pragma unroll
    for (int j = 0; j < 4; ++j)
        lacc[j] += __shfl_xor(lacc[j], 32);
    if (l < 32) {
        #pragma unroll
        for (int j = 0; j < 4; ++j) red[w][j][la] = lacc[j];
    }
    __syncthreads();
    if (t < 128) {
        int j = t >> 5;
        int c = t & 31;
        float L = 0.0f;
        #pragma unroll
        for (int ww = 0; ww < 8; ++ww) L += red[ww][j][c];
        atomicAdd(&Lg[(size_t)b * L_SEQ + ct4 * 128 + j * 32 + c], L);
    }
}

// grid = 8 b x 64 mtiles(32 m) = 512 blocks (b = bid&7), 256 thr = 4 waves
// (4 c-slices). ALL operands are coalesced records; NO barriers in the main
// loop. LDS 64 KB only for the epilogue cross-slice reduction (2 blocks/CU).
// invL computed on the fly with v_rcp_f32 (Lg now holds raw L).
__global__ __launch_bounds__(256, 2) void attend_fused(const short* __restrict__ Cf,
                                                       const short* __restrict__ Mf,
                                                       const short* __restrict__ Ctf,
                                                       const float* __restrict__ Lg,
                                                       const float* __restrict__ mn,
                                                       float* __restrict__ out) {
    __shared__ float red[4][4096];

    int bid = blockIdx.x;
    int b = bid & 7;
    int mtile = bid >> 3;       // 0..63
    int t = threadIdx.x;
    int w = t >> 6;             // ch
    int l = t & 63;
    int la = l & 31;
    int hi = l >> 5;
    int ch = w;

    // Hoist M B-frags from Mf record (mw = mtile) — same records stats read.
    bf16x8 mf[8];
    {
        const short* mfp = Mf + (size_t)((b * 64 + mtile) * 8) * 512 + l * 8;
        #pragma unroll
        for (int ks = 0; ks < 8; ++ks)
            mf[ks] = *(const bf16x8*)&mfp[(size_t)ks * 512];
    }

    f32x16 o[4];
    #pragma unroll
    for (int dg = 0; dg < 4; ++dg)
        #pragma unroll
        for (int r = 0; r < 16; ++r) o[dg][r] = 0.0f;

    const float* ilbase = Lg + (size_t)b * L_SEQ + ch * 32 + hi * 4;

    for (int cs = 0; cs < 16; ++cs) {
        const short* cfp = Cf + (size_t)(((b * 16 + cs) * 4 + ch) * 8) * 512 + l * 8;
        const short* tfp = Ctf + (size_t)((((b * 16 + cs) * 4 + ch) * 4) * 2) * 512 + l * 8;

        // PV A-frags: 8 coalesced record loads (independent of S, fly early).
        bf16x8 tv[4][2];
        #pragma unroll
        for (int dg = 0; dg < 4; ++dg)
            #pragma unroll
            for (int ks2 = 0; ks2 < 2; ++ks2)
                tv[dg][ks2] = *(const bf16x8*)&tfp[(size_t)(dg * 2 + ks2) * 512];

        // L for this window's 16 c's per lane (broadcast float4), -> invL.
        f32x4 ilv[4];
        #pragma unroll
        for (int q = 0; q < 4; ++q) {
            f32x4 lv = *(const f32x4*)&ilbase[cs * 128 + q * 8];
            #pragma unroll
            for (int e = 0; e < 4; ++e)
                ilv[q][e] = __builtin_amdgcn_rcpf(lv[e]);
        }

        // S-GEMM (swapped): D[i=c][j=m=la], A = Cf records.
        f32x16 s;
        #pragma unroll
        for (int r = 0; r < 16; ++r) s[r] = 0.0f;
        #pragma unroll
        for (int ks = 0; ks < 8; ++ks) {
            bf16x8 av = *(const bf16x8*)&cfp[(size_t)ks * 512];
            s = __builtin_amdgcn_mfma_f32_32x32x16_bf16(av, mf[ks], s, 0, 0, 0);
        }

        // P = exp(S-40) * invL[c] -> bf16 pairs. reg r=q*4+sub: c_local = sub+8q+4hi.
        unsigned u[4][2];
        #pragma unroll
        for (int q = 0; q < 4; ++q)
            #pragma unroll
            for (int jj = 0; jj < 2; ++jj) {
                float e0 = __expf(s[q * 4 + jj * 2]     - SHIFT) * ilv[q][jj * 2];
                float e1 = __expf(s[q * 4 + jj * 2 + 1] - SHIFT) * ilv[q][jj * 2 + 1];
                u[q][jj] = ((unsigned)(unsigned short)f2bf(e1) << 16)
                         |  (unsigned)(unsigned short)f2bf(e0);
            }

        // Half-wave exchange -> PV B-frags (c_local = ks2*16 + hi*8 + 0..7).
        bf16x8 pa[2];
        #pragma unroll
        for (int ks2 = 0; ks2 < 2; ++ks2) {
            unsigned a0 = u[2 * ks2][0],     a1 = u[2 * ks2][1];
            unsigned b0 = u[2 * ks2 + 1][0], b1 = u[2 * ks2 + 1][1];
            unsigned a0p = (unsigned)__shfl_xor((int)a0, 32);
            unsigned a1p = (unsigned)__shfl_xor((int)a1, 32);
            unsigned b0p = (unsigned)__shfl_xor((int)b0, 32);
            unsigned b1p = (unsigned)__shfl_xor((int)b1, 32);
            uint4v pw;
            pw.x = hi ? b0p : a0;
            pw.y = hi ? b1p : a1;
            pw.z = hi ? b0  : a0p;
            pw.w = hi ? b1  : a1p;
            pa[ks2] = __builtin_bit_cast(bf16x8, pw);
        }

        // PV: D2[i=d][j=m], A = tv (Ctf records), B = pa.
        #pragma unroll
        for (int dg = 0; dg < 4; ++dg)
            #pragma unroll
            for (int ks2 = 0; ks2 < 2; ++ks2)
                o[dg] = __builtin_amdgcn_mfma_f32_32x32x16_bf16(tv[dg][ks2], pa[ks2], o[dg], 0, 0, 0);
    }

    // Epilogue: per-wave partials -> LDS, sum 4 c-slices, out = main - sum.
    {
        float* base = red[w];
        #pragma unroll
        for (int dg = 0; dg < 4; ++dg)
            #pragma unroll
            for (int r = 0; r < 16; ++r) {
                int d = dg * 32 + (r & 3) + 8 * (r >> 2) + 4 * hi;
                base[d * 32 + la] = o[dg][r];
            }
    }
    __syncthreads();

    {
        int m  = t & 31;
        int dq = t >> 5;
        size_t gbase = ((size_t)(b * L_SEQ + mtile * 32 + m)) * DD + dq * 16;
        #pragma unroll
        for (int jq = 0; jq < 4; ++jq) {
            f32x4 v;
            #pragma unroll
            for (int e = 0; e < 4; ++e) {
                int idx = (dq * 16 + jq * 4 + e) * 32 + m;
                v[e] = red[0][idx] + red[1][idx] + red[2][idx] + red[3][idx];
            }
            f32x4 mv = *(const f32x4*)&mn[gbase + jq * 4];
            f32x4 ov;
            ov[0] = mv[0] - v[0]; ov[1] = mv[1] - v[1];
            ov[2] = mv[2] - v[2]; ov[3] = mv[3] - v[3];
            *(f32x4*)&out[gbase + jq * 4] = ov;
        }
    }
}

// ---------------------------------------------------------------------------
// Fallback path (round-2 kernels, tiny workspace)
// ---------------------------------------------------------------------------

__global__ __launch_bounds__(256, 4) void stats_fb(const float* __restrict__ ctx,
                                                   const float* __restrict__ mn,
                                                   float* __restrict__ Lg) {
    __shared__ short Cs[64 * LDA];
    __shared__ short Ms[64 * LDA];

    int bid = blockIdx.x;
    int mc = bid & 3;
    int ct = (bid >> 2) & 31;
    int b  = bid >> 7;
    int t = threadIdx.x;
    int w = t >> 6;
    int l = t & 63;
    int a15 = l & 15;
    int q = l >> 4;

    stage_tile<256>(Cs, ctx + ((size_t)b * L_SEQ + ct * 64) * DD, 64 * DD, t);

    float ls[4] = {0.f, 0.f, 0.f, 0.f};
    for (int mt = 0; mt < 8; ++mt) {
        __syncthreads();
        int m0 = (mc * 8 + mt) * 64;
        stage_tile<256>(Ms, mn + ((size_t)b * L_SEQ + m0) * DD, 64 * DD, t);
        __syncthreads();

        f32x4 acc[4] = {{0.f,0.f,0.f,0.f},{0.f,0.f,0.f,0.f},{0.f,0.f,0.f,0.f},{0.f,0.f,0.f,0.f}};
        #pragma unroll
        for (int ks = 0; ks < 4; ++ks) {
            int k0 = ks * 32 + q * 8;
            bf16x8 a = *(const bf16x8*)&Cs[(w * 16 + a15) * LDA + k0];
            #pragma unroll
            for (int g = 0; g < 4; ++g) {
                bf16x8 bb = *(const bf16x8*)&Ms[(g * 16 + a15) * LDA + k0];
                acc[g] = __builtin_amdgcn_mfma_f32_16x16x32_bf16(a, bb, acc[g], 0, 0, 0);
            }
        }
        #pragma unroll
        for (int g = 0; g < 4; ++g)
            #pragma unroll
            for (int r = 0; r < 4; ++r)
                ls[r] += __expf(acc[g][r] - SHIFT);
    }

    #pragma unroll
    for (int r = 0; r < 4; ++r) {
        float v = ls[r];
        v += __shfl_xor(v, 1);
        v += __shfl_xor(v, 2);
        v += __shfl_xor(v, 4);
        v += __shfl_xor(v, 8);
        ls[r] = v;
    }
    if (a15 == 0) {
        int c = ct * 64 + w * 16 + q * 4;
        #pragma unroll
        for (int r = 0; r < 4; ++r)
            atomicAdd(&Lg[(size_t)b * L_SEQ + c + r], ls[r]);
    }
}

__global__ __launch_bounds__(1024, 4) void attend_fb(const float* __restrict__ ctx,
                                                     const float* __restrict__ mn,
                                                     const float* __restrict__ Lg,
                                                     float* __restrict__ out) {
    __shared__ short Mt[64 * LDA];
    __shared__ short Cs[128 * LDA];
    __shared__ short Ct[128 * LDA];
    __shared__ short Ps[64 * LDA];
    __shared__ float invLs[128];

    int bid = blockIdx.x;
    int mtile = bid & 31;
    int b = bid >> 5;
    int m0 = mtile * 64;
    int t = threadIdx.x;
    int w = t >> 6;
    int l = t & 63;
    int a15 = l & 15;
    int q = l >> 4;
    int mg = w & 3;
    int pg = w >> 2;

    stage_tile<1024>(Mt, mn + ((size_t)b * L_SEQ + m0) * DD, 64 * DD, t);

    f32x4 oacc[2] = {{0.f,0.f,0.f,0.f},{0.f,0.f,0.f,0.f}};

    for (int cs = 0; cs < 16; ++cs) {
        int c0 = cs * 128;
        __syncthreads();
        stage_tile<1024>(Cs, ctx + ((size_t)b * L_SEQ + c0) * DD, 128 * DD, t);
        if (t < 128) invLs[t] = 1.0f / Lg[(size_t)b * L_SEQ + c0 + t];
        __syncthreads();

        {
            int cc = t & 127;
            int d0 = (t >> 7) * 16;
            #pragma unroll
            for (int hh = 0; hh < 2; ++hh) {
                bf16x8 v = *(const bf16x8*)&Cs[cc * LDA + d0 + hh * 8];
                #pragma unroll
                for (int j = 0; j < 8; ++j)
                    Ct[(d0 + hh * 8 + j) * LDA + cc] = v[j];
            }
        }

        f32x4 sacc[2] = {{0.f,0.f,0.f,0.f},{0.f,0.f,0.f,0.f}};
        #pragma unroll
        for (int ks = 0; ks < 4; ++ks) {
            int k0 = ks * 32 + q * 8;
            bf16x8 a = *(const bf16x8*)&Mt[(mg * 16 + a15) * LDA + k0];
            #pragma unroll
            for (int g = 0; g < 2; ++g) {
                bf16x8 bb = *(const bf16x8*)&Cs[((pg * 2 + g) * 16 + a15) * LDA + k0];
                sacc[g] = __builtin_amdgcn_mfma_f32_16x16x32_bf16(a, bb, sacc[g], 0, 0, 0);
            }
        }
        #pragma unroll
        for (int g = 0; g < 2; ++g) {
            int cl = (pg * 2 + g) * 16 + a15;
            float il = invLs[cl];
            #pragma unroll
            for (int r = 0; r < 4; ++r) {
                float p = __expf(sacc[g][r] - SHIFT) * il;
                Ps[(mg * 16 + q * 4 + r) * LDA + cl] = f2bf(p);
            }
        }
        __syncthreads();

        #pragma unroll
        for (int ks = 0; ks < 4; ++ks) {
            int k0 = ks * 32 + q * 8;
            bf16x8 a = *(const bf16x8*)&Ps[(mg * 16 + a15) * LDA + k0];
            #pragma unroll
            for (int g = 0; g < 2; ++g) {
                bf16x8 bb = *(const bf16x8*)&Ct[((pg * 2 + g) * 16 + a15) * LDA + k0];
                oacc[g] = __builtin_amdgcn_mfma_f32_16x16x32_bf16(a, bb, oacc[g], 0, 0, 0);
            }
        }
    }

    #pragma unroll
    for (int g = 0; g < 2; ++g) {
        int dl = (pg * 2 + g) * 16 + a15;
        #pragma unroll
        for (int r = 0; r < 4; ++r) {
            int ml = mg * 16 + q * 4 + r;
            size_t idx = ((size_t)b * L_SEQ + m0 + ml) * DD + dl;
            out[idx] = mn[idx] - oacc[g][r];
        }
    }
}

// ---------------------------------------------------------------------------

extern "C" void kernel_launch(void* const* d_in, const int* in_sizes, int n_in,
                              void* d_out, int out_size, void* d_ws, size_t ws_size,
                              hipStream_t stream) {
    const float* ctx = (const float*)d_in[0];  // (B, Lc, D)
    const float* mn  = (const float*)d_in[1];  // (B, Lm, D)
    float* out = (float*)d_out;                // (B, Lm, D)

    // Workspace: Lg 64 KB | Cf 4 MB | Mf 4 MB | Ctf 4 MB
    const size_t LG_BYTES = (size_t)BATCH * L_SEQ * sizeof(float);
    const size_t BF_BYTES = (size_t)BATCH * L_SEQ * DD * sizeof(short);
    const size_t NEED = LG_BYTES + 3 * BF_BYTES;

    float* Lg = (float*)d_ws;

    if (ws_size >= NEED) {
        short* Cf  = (short*)((char*)d_ws + LG_BYTES);
        short* Mf  = (short*)((char*)d_ws + LG_BYTES + BF_BYTES);
        short* Ctf = (short*)((char*)d_ws + LG_BYTES + 2 * BF_BYTES);
        convert_kernel<<<1024, 256, 0, stream>>>(ctx, mn, Cf, Mf, Ctf, Lg);
        stats_kernel<<<256, 512, 0, stream>>>(Cf, Mf, Lg);
        attend_fused<<<512, 256, 0, stream>>>(Cf, Mf, Ctf, Lg, mn, out);
    } else {
        int nL = BATCH * L_SEQ;
        zero_kernel<<<(nL + 255) / 256, 256, 0, stream>>>(Lg, nL);
        stats_fb<<<BATCH * 32 * 4, 256, 0, stream>>>(ctx, mn, Lg);
        attend_fb<<<BATCH * 32, 1024, 0, stream>>>(ctx, mn, Lg, out);
    }
}